// Round 5
// baseline (777.124 us; speedup 1.0000x reference)
//
#include <hip/hip_runtime.h>
#include <math.h>

#define G_N 50000
#define D_S 3
#define HC 64
#define IN_DIM 256
#define OUT_DIM 40
#define NL 4
#define NNZV 2400000
#define NN (G_N * D_S)   // 150000
#define ROWS_PER_GRP (NN / 8)   // 18750

typedef __attribute__((ext_vector_type(8))) short bf16x8;
typedef __attribute__((ext_vector_type(4))) float f32x4;

__device__ __forceinline__ float elu_f(float v) {
    return v > 0.0f ? v : expm1f(v);
}

__device__ __forceinline__ unsigned short f2bf(float f) {
    unsigned u = __float_as_uint(f);
    return (unsigned short)((u + 0x7FFF + ((u >> 16) & 1)) >> 16);
}

// ---------------- lin1: out[g, j] = elu(sum_k x[g,k] * W[j,k] + b[j]); all 192 cols per block
__global__ __launch_bounds__(256) void lin1_gemm(const float* __restrict__ x,
        const float* __restrict__ W, const float* __restrict__ b,
        float* __restrict__ out) {
    const int K = IN_DIM;
    __shared__ float As[32][65];
    __shared__ float Bs[32][200];   // 192 cols + pad
    int tid = threadIdx.x;
    int tx = tid & 15, ty = tid >> 4;
    int m0 = blockIdx.x * 64;

    float acc[4][12] = {};
    int kslot = tid & 7;
    int row   = tid >> 3;

    for (int k0 = 0; k0 < K; k0 += 32) {
        #pragma unroll
        for (int pass = 0; pass < 2; ++pass) {
            int r = row + pass * 32;
            int gr = m0 + r;
            float4 v = make_float4(0.f, 0.f, 0.f, 0.f);
            if (gr < G_N) v = *(const float4*)(x + (size_t)gr * K + k0 + kslot * 4);
            As[kslot*4+0][r] = v.x; As[kslot*4+1][r] = v.y;
            As[kslot*4+2][r] = v.z; As[kslot*4+3][r] = v.w;
        }
        #pragma unroll
        for (int pass = 0; pass < 6; ++pass) {
            int j = row + pass * 32;
            float4 w4 = *(const float4*)(W + (size_t)j * K + k0 + kslot * 4);
            Bs[kslot*4+0][j] = w4.x; Bs[kslot*4+1][j] = w4.y;
            Bs[kslot*4+2][j] = w4.z; Bs[kslot*4+3][j] = w4.w;
        }
        __syncthreads();
        #pragma unroll 4
        for (int k = 0; k < 32; ++k) {
            float4 a4 = *(const float4*)&As[k][ty*4];
            float av[4] = {a4.x, a4.y, a4.z, a4.w};
            #pragma unroll
            for (int s = 0; s < 3; ++s) {
                float4 b4 = *(const float4*)&Bs[k][s*64 + tx*4];
                float bv[4] = {b4.x, b4.y, b4.z, b4.w};
                #pragma unroll
                for (int i = 0; i < 4; ++i)
                    #pragma unroll
                    for (int q = 0; q < 4; ++q)
                        acc[i][s*4+q] = fmaf(av[i], bv[q], acc[i][s*4+q]);
            }
        }
        __syncthreads();
    }

    float bi[12];
    #pragma unroll
    for (int s = 0; s < 3; ++s) {
        float4 bias = *(const float4*)(b + s*64 + tx*4);
        bi[s*4+0]=bias.x; bi[s*4+1]=bias.y; bi[s*4+2]=bias.z; bi[s*4+3]=bias.w;
    }
    #pragma unroll
    for (int i = 0; i < 4; ++i) {
        int gr = m0 + ty*4 + i;
        if (gr < G_N) {
            #pragma unroll
            for (int s = 0; s < 3; ++s) {
                float4 o;
                o.x = elu_f(acc[i][s*4+0] + bi[s*4+0]);
                o.y = elu_f(acc[i][s*4+1] + bi[s*4+1]);
                o.z = elu_f(acc[i][s*4+2] + bi[s*4+2]);
                o.w = elu_f(acc[i][s*4+3] + bi[s*4+3]);
                *(float4*)(out + (size_t)gr * 192 + s*64 + tx*4) = o;
            }
        }
    }
}

// ---------------- transform via MFMA bf16: tb[n,j] = bf16(sum_c A[n,c]*Wr[j,c])
// A[g*3+e,c] = sum_d lw[e,d]*h0[g*3+d,c]  (mixed in fp32, cast bf16 into LDS)
__global__ __launch_bounds__(256) void transform_mfma(const float* __restrict__ h0,
        const float* __restrict__ lw, const float* __restrict__ Wr,
        unsigned short* __restrict__ tb) {
    __shared__ __align__(16) unsigned short Asb[64][72];  // [row][k], pad 64->72
    __shared__ __align__(16) unsigned short Bsb[64][72];  // [outcol j][k=c]
    int tid = threadIdx.x;
    int r0 = blockIdx.x * 64;

    float L[9];
    #pragma unroll
    for (int i = 0; i < 9; ++i) L[i] = lw[i];

    // stage B: Bsb[j][c] = bf16(Wr[j*64+c])
    #pragma unroll
    for (int p = 0; p < 16; ++p) {
        int idx = p * 256 + tid;
        Bsb[idx >> 6][idx & 63] = f2bf(Wr[idx]);
    }
    // stage A (left-mixed)
    #pragma unroll
    for (int p = 0; p < 16; ++p) {
        int idx = p * 256 + tid;
        int r = idx >> 6, c = idx & 63;
        int gr = r0 + r;
        float m = 0.0f;
        if (gr < NN) {
            int g = gr / 3, e = gr - g * 3;
            const float* base = h0 + (size_t)(g * 3) * HC + c;
            m = L[e*3+0]*base[0] + L[e*3+1]*base[HC] + L[e*3+2]*base[2*HC];
        }
        Asb[r][c] = f2bf(m);
    }
    __syncthreads();

    int w = tid >> 6, lane = tid & 63;
    int l15 = lane & 15, kg = lane >> 4;

    f32x4 acc[4];
    #pragma unroll
    for (int nb = 0; nb < 4; ++nb) acc[nb] = (f32x4){0.f, 0.f, 0.f, 0.f};

    #pragma unroll
    for (int ks = 0; ks < 2; ++ks) {
        bf16x8 af = *(const bf16x8*)&Asb[w*16 + l15][ks*32 + kg*8];
        #pragma unroll
        for (int nb = 0; nb < 4; ++nb) {
            bf16x8 bfv = *(const bf16x8*)&Bsb[nb*16 + l15][ks*32 + kg*8];
            acc[nb] = __builtin_amdgcn_mfma_f32_16x16x32_bf16(af, bfv, acc[nb], 0, 0, 0);
        }
    }

    // D layout: col = lane&15, row = (lane>>4)*4 + reg
    #pragma unroll
    for (int nb = 0; nb < 4; ++nb) {
        #pragma unroll
        for (int i = 0; i < 4; ++i) {
            int rr = r0 + w*16 + kg*4 + i;
            if (rr < NN) tb[(size_t)rr * HC + nb*16 + l15] = f2bf(acc[nb][i]);
        }
    }
}

// ---------------- CSR build (XCD row-range groups; nt loads keep L2 for writes) ----------------
__global__ __launch_bounds__(256) void hist_grp_k(const int* __restrict__ rows,
        int* __restrict__ cnt) {
    int g = blockIdx.x & 7;
    int s = blockIdx.x >> 3;
    int lo = g * ROWS_PER_GRP, hi = lo + ROWS_PER_GRP;
    int stride = (gridDim.x >> 3) * 256;
    for (int i = s * 256 + threadIdx.x; i < NNZV; i += stride) {
        int r = __builtin_nontemporal_load(rows + i);
        if (r >= lo && r < hi) atomicAdd(&cnt[r], 1);
    }
}

__global__ __launch_bounds__(256) void scan_block_k(const int* __restrict__ cnt,
        int* __restrict__ rp, int* __restrict__ bsum) {
    __shared__ int s[256];
    int base = blockIdx.x * 1024;
    int t = threadIdx.x;
    int v[4]; int sum = 0;
    #pragma unroll
    for (int j = 0; j < 4; ++j) {
        int idx = base + t * 4 + j;
        v[j] = (idx < NN) ? cnt[idx] : 0;
        sum += v[j];
    }
    s[t] = sum; __syncthreads();
    #pragma unroll
    for (int off = 1; off < 256; off <<= 1) {
        int x = 0;
        if (t >= off) x = s[t - off];
        __syncthreads();
        if (t >= off) s[t] += x;
        __syncthreads();
    }
    int excl = s[t] - sum;
    if (t == 255) bsum[blockIdx.x] = s[255];
    int run = excl;
    #pragma unroll
    for (int j = 0; j < 4; ++j) {
        int idx = base + t * 4 + j;
        if (idx < NN) rp[idx] = run;
        run += v[j];
    }
}

__global__ __launch_bounds__(256) void scan_top_k(int* __restrict__ bsum, int nb) {
    __shared__ int s[256];
    int t = threadIdx.x;
    int v = (t < nb) ? bsum[t] : 0;
    s[t] = v; __syncthreads();
    #pragma unroll
    for (int off = 1; off < 256; off <<= 1) {
        int x = 0;
        if (t >= off) x = s[t - off];
        __syncthreads();
        if (t >= off) s[t] += x;
        __syncthreads();
    }
    if (t < nb) bsum[t] = s[t] - v;
}

__global__ __launch_bounds__(256) void scan_add_k(int* __restrict__ rp, const int* __restrict__ bsum) {
    int idx = blockIdx.x * 256 + threadIdx.x;
    if (idx < NN) rp[idx] += bsum[idx >> 10];
    else if (idx == NN) rp[NN] = NNZV;
}

__global__ __launch_bounds__(256) void scatter_grp_k(const int* __restrict__ rows,
        const int* __restrict__ cols, const float* __restrict__ vals,
        int* __restrict__ wo, int2* __restrict__ pcv) {
    int g = blockIdx.x & 7;
    int s = blockIdx.x >> 3;
    int lo = g * ROWS_PER_GRP, hi = lo + ROWS_PER_GRP;
    int stride = (gridDim.x >> 3) * 256;
    for (int i = s * 256 + threadIdx.x; i < NNZV; i += stride) {
        int r = __builtin_nontemporal_load(rows + i);
        if (r >= lo && r < hi) {
            int c = __builtin_nontemporal_load(cols + i);
            float v = __builtin_nontemporal_load(vals + i);
            int p = atomicAdd(&wo[r], 1);
            pcv[p] = make_int2(c, __float_as_int(v));   // normal store: accumulate in L2
        }
    }
}

// ---------------- fused CSR SpMM + elu + gated residual: h0 = gate*h0 - elu(L@t)
__global__ __launch_bounds__(256) void spmm_csr_fused(const int* __restrict__ rp,
        const long long* __restrict__ pcv, const unsigned short* __restrict__ tb,
        float* __restrict__ h0, const float* __restrict__ eps, int l) {
    int w = blockIdx.x * 4 + (threadIdx.x >> 6);
    int lane = threadIdx.x & 63;
    if (w >= NN) return;
    int s = rp[w], e = rp[w + 1];
    float acc = 0.0f;
    for (int cb = s; cb < e; cb += 64) {
        int n = e - cb; if (n > 64) n = 64;
        long long packed = 0;
        if (lane < n) packed = __builtin_nontemporal_load(pcv + cb + lane);
        int cvx = (int)packed;
        int cvy = (int)(packed >> 32);
        for (int j0 = 0; j0 < n; j0 += 8) {
            float hv[8], vv[8];
            #pragma unroll
            for (int u = 0; u < 8; ++u) {
                int   c = __shfl(cvx, j0 + u);
                vv[u]   = __int_as_float(__shfl(cvy, j0 + u));
                hv[u]   = __uint_as_float((unsigned)tb[(size_t)c * HC + lane] << 16);
            }
            #pragma unroll
            for (int u = 0; u < 8; ++u) acc = fmaf(vv[u], hv[u], acc);
        }
    }
    float hnew = acc > 0.0f ? acc : expm1f(acc);
    int d = w % 3;
    float gate = 1.0f + tanhf(eps[l * 3 + d]);
    size_t idx = (size_t)w * HC + lane;
    float h0v = __builtin_nontemporal_load(h0 + idx);
    __builtin_nontemporal_store(gate * h0v - hnew, h0 + idx);
}

// ---------------- lin2 (tiled GEMM, N padded 40->64) + fused log_softmax
__global__ __launch_bounds__(256) void lin2_ls_gemm(const float* __restrict__ h,
        const float* __restrict__ W, const float* __restrict__ b,
        float* __restrict__ out) {
    const int K = 192;
    __shared__ float As[32][65];
    __shared__ float Bs[32][65];
    int tid = threadIdx.x;
    int tx = tid & 15, ty = tid >> 4;
    int m0 = blockIdx.x * 64;

    float acc[4][4] = {};
    int kslot = tid & 7;
    int row   = tid >> 3;

    for (int k0 = 0; k0 < K; k0 += 32) {
        #pragma unroll
        for (int pass = 0; pass < 2; ++pass) {
            int r = row + pass * 32;
            int gr = m0 + r;
            float4 v = make_float4(0.f, 0.f, 0.f, 0.f);
            if (gr < G_N) v = *(const float4*)(h + (size_t)gr * K + k0 + kslot * 4);
            As[kslot*4+0][r] = v.x; As[kslot*4+1][r] = v.y;
            As[kslot*4+2][r] = v.z; As[kslot*4+3][r] = v.w;

            int j = r;
            float4 w4 = make_float4(0.f, 0.f, 0.f, 0.f);
            if (j < OUT_DIM) w4 = *(const float4*)(W + (size_t)j * K + k0 + kslot * 4);
            Bs[kslot*4+0][j] = w4.x; Bs[kslot*4+1][j] = w4.y;
            Bs[kslot*4+2][j] = w4.z; Bs[kslot*4+3][j] = w4.w;
        }
        __syncthreads();
        #pragma unroll 8
        for (int k = 0; k < 32; ++k) {
            float4 a4 = *(const float4*)&As[k][ty*4];
            float4 b4 = *(const float4*)&Bs[k][tx*4];
            float av[4] = {a4.x, a4.y, a4.z, a4.w};
            float bv[4] = {b4.x, b4.y, b4.z, b4.w};
            #pragma unroll
            for (int i = 0; i < 4; ++i)
                #pragma unroll
                for (int j = 0; j < 4; ++j)
                    acc[i][j] = fmaf(av[i], bv[j], acc[i][j]);
        }
        __syncthreads();
    }

    bool validc = (tx < 10);
    float bi[4];
    #pragma unroll
    for (int j = 0; j < 4; ++j) bi[j] = validc ? b[tx*4+j] : 0.0f;

    #pragma unroll
    for (int i = 0; i < 4; ++i) {
        int gr = m0 + ty*4 + i;
        float v[4];
        float mymax = -INFINITY;
        #pragma unroll
        for (int j = 0; j < 4; ++j) {
            v[j] = acc[i][j] + bi[j];
            if (validc) mymax = fmaxf(mymax, v[j]);
        }
        #pragma unroll
        for (int off = 1; off < 16; off <<= 1) mymax = fmaxf(mymax, __shfl_xor(mymax, off));
        float s = 0.0f;
        if (validc) {
            #pragma unroll
            for (int j = 0; j < 4; ++j) s += expf(v[j] - mymax);
        }
        #pragma unroll
        for (int off = 1; off < 16; off <<= 1) s += __shfl_xor(s, off);
        float lse = mymax + logf(s);
        if (gr < G_N && validc) {
            float4 o = make_float4(v[0]-lse, v[1]-lse, v[2]-lse, v[3]-lse);
            *(float4*)(out + (size_t)gr * OUT_DIM + tx*4) = o;
        }
    }
}

extern "C" void kernel_launch(void* const* d_in, const int* in_sizes, int n_in,
                              void* d_out, int out_size, void* d_ws, size_t ws_size,
                              hipStream_t stream) {
    const float* x      = (const float*)d_in[0];
    const int*   rows   = (const int*)d_in[1];
    const int*   cols   = (const int*)d_in[2];
    const float* vals   = (const float*)d_in[3];
    const float* lin1_w = (const float*)d_in[4];
    const float* lin1_b = (const float*)d_in[5];
    const float* left_w = (const float*)d_in[6];
    const float* right_w= (const float*)d_in[7];
    const float* eps    = (const float*)d_in[8];
    const float* lin2_w = (const float*)d_in[9];
    const float* lin2_b = (const float*)d_in[10];
    float* out = (float*)d_out;

    size_t bufElems = (size_t)NN * HC;                     // 9.6M
    float* h0 = (float*)d_ws;                              // 38.4 MB
    unsigned short* tb = (unsigned short*)(h0 + bufElems); // 19.2 MB (bf16)
    int*   rp   = (int*)(tb + bufElems);                   // NN+1
    int*   wo   = rp + 150016;
    int*   bsum = wo + 150016;
    int2*  pcv  = (int2*)(bsum + 256);                     // 19.2 MB

    dim3 b256(256);
    const int NB_SCAN = (NN + 1023) / 1024;                // 147
    const int NB_GRP  = 8 * 2344;

    // --- CSR build (once; reused by all 4 layers) ---
    hipMemsetAsync(wo, 0, (size_t)NN * sizeof(int), stream);
    hist_grp_k<<<dim3(NB_GRP), b256, 0, stream>>>(rows, wo);
    scan_block_k<<<dim3(NB_SCAN), b256, 0, stream>>>(wo, rp, bsum);
    scan_top_k<<<dim3(1), b256, 0, stream>>>(bsum, NB_SCAN);
    scan_add_k<<<dim3((NN + 256) / 256 + 1), b256, 0, stream>>>(rp, bsum);
    hipMemcpyAsync(wo, rp, (size_t)NN * sizeof(int), hipMemcpyDeviceToDevice, stream);
    scatter_grp_k<<<dim3(NB_GRP), b256, 0, stream>>>(rows, cols, vals, wo, pcv);

    // --- lin1 -> h0 ---
    lin1_gemm<<<dim3((G_N + 63) / 64), b256, 0, stream>>>(x, lin1_w, lin1_b, h0);

    for (int l = 0; l < NL; ++l) {
        transform_mfma<<<dim3((NN + 63) / 64), b256, 0, stream>>>(
            h0, left_w + l * 9, right_w + l * HC * HC, tb);
        spmm_csr_fused<<<dim3((NN + 3) / 4), b256, 0, stream>>>(
            rp, (const long long*)pcv, tb, h0, eps, l);
    }

    lin2_ls_gemm<<<dim3((G_N + 63) / 64), b256, 0, stream>>>(h0, lin2_w, lin2_b, out);
}

// Round 7
// 769.043 us; speedup vs baseline: 1.0105x; 1.0105x over previous
//
#include <hip/hip_runtime.h>
#include <math.h>

#define G_N 50000
#define D_S 3
#define HC 64
#define IN_DIM 256
#define OUT_DIM 40
#define NL 4
#define NNZV 2400000
#define NN (G_N * D_S)          // 150000
#define RPG (NN / 8)            // 18750 rows per bucket/XCD
#define BCAP 332768             // bucket capacity (mean 300000, +60 sigma)
#define PCV_CAP 4200000         // padded CSR capacity (mean ~3.6M)

typedef __attribute__((ext_vector_type(8))) short bf16x8;
typedef __attribute__((ext_vector_type(4))) float f32x4;

__device__ __forceinline__ float elu_f(float v) {
    return v > 0.0f ? v : expm1f(v);
}

__device__ __forceinline__ unsigned short f2bf(float f) {
    unsigned u = __float_as_uint(f);
    return (unsigned short)((u + 0x7FFF + ((u >> 16) & 1)) >> 16);
}

// ---------------- lin1 via MFMA bf16: h0[g,j] = elu(x@W1^T + b), M=50000, N=192, K=256
__global__ __launch_bounds__(256) void lin1_mfma(const float* __restrict__ x,
        const float* __restrict__ W, const float* __restrict__ b,
        float* __restrict__ out) {
    __shared__ __align__(16) unsigned short Ab[2][64][72];
    __shared__ __align__(16) unsigned short Bb[2][192][72];
    int tid = threadIdx.x;
    int m0 = blockIdx.x * 64;
    int w = tid >> 6, lane = tid & 63;
    int l15 = lane & 15, kg = lane >> 4;

    f32x4 acc[12];
    #pragma unroll
    for (int nb = 0; nb < 12; ++nb) acc[nb] = (f32x4){0.f, 0.f, 0.f, 0.f};

    auto stage = [&](int kt, int bf) {
        int k0 = kt * 64;
        #pragma unroll
        for (int p = 0; p < 4; ++p) {           // A: 64 rows x 64 k
            int fid = p * 256 + tid;
            int r = fid >> 4, kq = fid & 15;
            int gr = m0 + r;
            float4 v = make_float4(0.f, 0.f, 0.f, 0.f);
            if (gr < G_N) v = *(const float4*)(x + (size_t)gr * IN_DIM + k0 + kq * 4);
            Ab[bf][r][kq*4+0] = f2bf(v.x); Ab[bf][r][kq*4+1] = f2bf(v.y);
            Ab[bf][r][kq*4+2] = f2bf(v.z); Ab[bf][r][kq*4+3] = f2bf(v.w);
        }
        #pragma unroll
        for (int p = 0; p < 12; ++p) {          // B: 192 cols x 64 k
            int fid = p * 256 + tid;
            int j = fid >> 4, kq = fid & 15;
            float4 v = *(const float4*)(W + (size_t)j * IN_DIM + k0 + kq * 4);
            Bb[bf][j][kq*4+0] = f2bf(v.x); Bb[bf][j][kq*4+1] = f2bf(v.y);
            Bb[bf][j][kq*4+2] = f2bf(v.z); Bb[bf][j][kq*4+3] = f2bf(v.w);
        }
    };

    stage(0, 0);
    __syncthreads();
    int bf = 0;
    for (int kt = 0; kt < 4; ++kt) {
        if (kt < 3) stage(kt + 1, bf ^ 1);
        #pragma unroll
        for (int ks = 0; ks < 2; ++ks) {
            bf16x8 af = *(const bf16x8*)&Ab[bf][w*16 + l15][ks*32 + kg*8];
            #pragma unroll
            for (int nb = 0; nb < 12; ++nb) {
                bf16x8 bv = *(const bf16x8*)&Bb[bf][nb*16 + l15][ks*32 + kg*8];
                acc[nb] = __builtin_amdgcn_mfma_f32_16x16x32_bf16(af, bv, acc[nb], 0, 0, 0);
            }
        }
        __syncthreads();
        bf ^= 1;
    }

    // D layout: col = lane&15, row = (lane>>4)*4 + reg
    #pragma unroll
    for (int nb = 0; nb < 12; ++nb) {
        float bias = b[nb*16 + l15];
        #pragma unroll
        for (int i = 0; i < 4; ++i) {
            int gr = m0 + w*16 + kg*4 + i;
            if (gr < G_N)
                out[(size_t)gr * 192 + nb*16 + l15] = elu_f(acc[nb][i] + bias);
        }
    }
}

// ---------------- transform via MFMA bf16: tb[n,j] = bf16(sum_c A[n,c]*Wr[j,c])
__global__ __launch_bounds__(256) void transform_mfma(const float* __restrict__ h0,
        const float* __restrict__ lw, const float* __restrict__ Wr,
        unsigned short* __restrict__ tb) {
    __shared__ __align__(16) unsigned short Asb[64][72];
    __shared__ __align__(16) unsigned short Bsb[64][72];
    int tid = threadIdx.x;
    int r0 = blockIdx.x * 64;

    float L[9];
    #pragma unroll
    for (int i = 0; i < 9; ++i) L[i] = lw[i];

    #pragma unroll
    for (int p = 0; p < 16; ++p) {
        int idx = p * 256 + tid;
        Bsb[idx >> 6][idx & 63] = f2bf(Wr[idx]);
    }
    #pragma unroll
    for (int p = 0; p < 16; ++p) {
        int idx = p * 256 + tid;
        int r = idx >> 6, c = idx & 63;
        int gr = r0 + r;
        float m = 0.0f;
        if (gr < NN) {
            int g = gr / 3, e = gr - g * 3;
            const float* base = h0 + (size_t)(g * 3) * HC + c;
            m = L[e*3+0]*base[0] + L[e*3+1]*base[HC] + L[e*3+2]*base[2*HC];
        }
        Asb[r][c] = f2bf(m);
    }
    __syncthreads();

    int w = tid >> 6, lane = tid & 63;
    int l15 = lane & 15, kg = lane >> 4;

    f32x4 acc[4];
    #pragma unroll
    for (int nb = 0; nb < 4; ++nb) acc[nb] = (f32x4){0.f, 0.f, 0.f, 0.f};

    #pragma unroll
    for (int ks = 0; ks < 2; ++ks) {
        bf16x8 af = *(const bf16x8*)&Asb[w*16 + l15][ks*32 + kg*8];
        #pragma unroll
        for (int nb = 0; nb < 4; ++nb) {
            bf16x8 bfv = *(const bf16x8*)&Bsb[nb*16 + l15][ks*32 + kg*8];
            acc[nb] = __builtin_amdgcn_mfma_f32_16x16x32_bf16(af, bfv, acc[nb], 0, 0, 0);
        }
    }

    #pragma unroll
    for (int nb = 0; nb < 4; ++nb) {
        #pragma unroll
        for (int i = 0; i < 4; ++i) {
            int rr = r0 + w*16 + kg*4 + i;
            if (rr < NN) tb[(size_t)rr * HC + nb*16 + l15] = f2bf(acc[nb][i]);
        }
    }
}

// ---------------- CSR build: two-phase XCD-bucketed ----------------
__global__ void init_gcur_k(int* gcur) {
    if (threadIdx.x < 8) gcur[threadIdx.x] = threadIdx.x * BCAP;
}

// Phase A: partition COO into 8 row-range buckets (sequential writes)
__global__ __launch_bounds__(256) void bucket_part_k(const int* __restrict__ rows,
        const int* __restrict__ cols, const float* __restrict__ vals,
        int* __restrict__ gcur, int* __restrict__ rbuf, long long* __restrict__ cvbuf) {
    __shared__ int cnt8[8];
    __shared__ int base8[8];
    int tid = threadIdx.x;
    int c0 = blockIdx.x * 2048;
    if (tid < 8) cnt8[tid] = 0;
    __syncthreads();
    #pragma unroll
    for (int it = 0; it < 8; ++it) {
        int i = c0 + it * 256 + tid;
        if (i < NNZV) {
            int r = __builtin_nontemporal_load(rows + i);
            atomicAdd(&cnt8[r / RPG], 1);
        }
    }
    __syncthreads();
    if (tid < 8) {
        base8[tid] = atomicAdd(&gcur[tid], cnt8[tid]);
        cnt8[tid] = 0;
    }
    __syncthreads();
    #pragma unroll
    for (int it = 0; it < 8; ++it) {
        int i = c0 + it * 256 + tid;
        if (i < NNZV) {
            int r = rows[i];                                  // L2-hot re-read
            int c = __builtin_nontemporal_load(cols + i);
            float v = __builtin_nontemporal_load(vals + i);
            int bkt = r / RPG;
            int pos = base8[bkt] + atomicAdd(&cnt8[bkt], 1);
            rbuf[pos] = r;
            cvbuf[pos] = ((long long)__float_as_int(v) << 32) | (unsigned)c;
        }
    }
}

// Phase B: per-bucket histogram (XCD-local)
__global__ __launch_bounds__(256) void hist_bucket_k(const int* __restrict__ rbuf,
        const int* __restrict__ gcur, int* __restrict__ cnt) {
    int g = blockIdx.x & 7;
    int s = blockIdx.x >> 3;
    int base = g * BCAP;
    int bsz = gcur[g] - base;
    int stride = (gridDim.x >> 3) * 256;
    for (int i = s * 256 + threadIdx.x; i < bsz; i += stride) {
        int r = __builtin_nontemporal_load(rbuf + base + i);
        atomicAdd(&cnt[r], 1);
    }
}

// scan with pad-to-16 of per-row counts
__global__ __launch_bounds__(256) void scan_block_k(const int* __restrict__ cnt,
        int* __restrict__ rp, int* __restrict__ bsum) {
    __shared__ int s[256];
    int base = blockIdx.x * 1024;
    int t = threadIdx.x;
    int v[4]; int sum = 0;
    #pragma unroll
    for (int j = 0; j < 4; ++j) {
        int idx = base + t * 4 + j;
        int c = (idx < NN) ? cnt[idx] : 0;
        v[j] = (c + 15) & ~15;                   // pad row to multiple of 16
        sum += v[j];
    }
    s[t] = sum; __syncthreads();
    #pragma unroll
    for (int off = 1; off < 256; off <<= 1) {
        int x = 0;
        if (t >= off) x = s[t - off];
        __syncthreads();
        if (t >= off) s[t] += x;
        __syncthreads();
    }
    int excl = s[t] - sum;
    if (t == 255) bsum[blockIdx.x] = s[255];
    int run = excl;
    #pragma unroll
    for (int j = 0; j < 4; ++j) {
        int idx = base + t * 4 + j;
        if (idx < NN) rp[idx] = run;
        run += v[j];
    }
}

__global__ __launch_bounds__(256) void scan_top_k(int* __restrict__ bsum, int nb) {
    __shared__ int s[256];
    int t = threadIdx.x;
    int v = (t < nb) ? bsum[t] : 0;
    s[t] = v; __syncthreads();
    #pragma unroll
    for (int off = 1; off < 256; off <<= 1) {
        int x = 0;
        if (t >= off) x = s[t - off];
        __syncthreads();
        if (t >= off) s[t] += x;
        __syncthreads();
    }
    if (t == nb - 1) bsum[255] = s[t];           // inclusive total (padded nnz)
    if (t < nb) bsum[t] = s[t] - v;
}

__global__ __launch_bounds__(256) void scan_add_k(int* __restrict__ rp, const int* __restrict__ bsum) {
    int idx = blockIdx.x * 256 + threadIdx.x;
    if (idx < NN) rp[idx] += bsum[idx >> 10];
    else if (idx == NN) rp[NN] = bsum[255];
}

// Phase E: per-bucket scatter into padded CSR (XCD-local)
__global__ __launch_bounds__(256) void scatter_bucket_k(const int* __restrict__ rbuf,
        const long long* __restrict__ cvbuf, const int* __restrict__ gcur,
        int* __restrict__ wo, long long* __restrict__ pcv) {
    int g = blockIdx.x & 7;
    int s = blockIdx.x >> 3;
    int base = g * BCAP;
    int bsz = gcur[g] - base;
    int stride = (gridDim.x >> 3) * 256;
    for (int i = s * 256 + threadIdx.x; i < bsz; i += stride) {
        int r = __builtin_nontemporal_load(rbuf + base + i);
        long long cv = __builtin_nontemporal_load(cvbuf + base + i);
        int p = atomicAdd(&wo[r], 1);
        pcv[p] = cv;
    }
}

// ---------------- fused padded-CSR SpMM + elu + gated residual: h0 = gate*h0 - elu(L@t)
__global__ __launch_bounds__(256) void spmm_csr_fused(const int* __restrict__ rp,
        const long long* __restrict__ pcv, const unsigned short* __restrict__ tb,
        float* __restrict__ h0, const float* __restrict__ eps, int l) {
    int w = blockIdx.x * 4 + (threadIdx.x >> 6);
    int lane = threadIdx.x & 63;
    if (w >= NN) return;
    int s = rp[w], e = rp[w + 1];                // e-s is a multiple of 16
    float acc = 0.0f;
    for (int cb = s; cb < e; cb += 64) {
        int n = e - cb; if (n > 64) n = 64;      // n is a multiple of 16
        long long packed = 0;
        if (lane < n) packed = __builtin_nontemporal_load(pcv + cb + lane);
        int cvx = (int)packed;                   // col
        int cvy = (int)(packed >> 32);           // val bits
        for (int j0 = 0; j0 < n; j0 += 16) {
            float hv[16], vv[16];
            #pragma unroll
            for (int u = 0; u < 16; ++u) {
                int   c = __shfl(cvx, j0 + u);
                vv[u]   = __int_as_float(__shfl(cvy, j0 + u));
                hv[u]   = __uint_as_float((unsigned)tb[(size_t)c * HC + lane] << 16);
            }
            #pragma unroll
            for (int u = 0; u < 16; ++u) acc = fmaf(vv[u], hv[u], acc);
        }
    }
    float hnew = acc > 0.0f ? acc : expm1f(acc);
    int d = w % 3;
    float gate = 1.0f + tanhf(eps[l * 3 + d]);
    size_t idx = (size_t)w * HC + lane;
    float h0v = __builtin_nontemporal_load(h0 + idx);
    __builtin_nontemporal_store(gate * h0v - hnew, h0 + idx);
}

// ---------------- lin2 (tiled GEMM, N padded 40->64) + fused log_softmax
__global__ __launch_bounds__(256) void lin2_ls_gemm(const float* __restrict__ h,
        const float* __restrict__ W, const float* __restrict__ b,
        float* __restrict__ out) {
    const int K = 192;
    __shared__ float As[32][65];
    __shared__ float Bs[32][65];
    int tid = threadIdx.x;
    int tx = tid & 15, ty = tid >> 4;
    int m0 = blockIdx.x * 64;

    float acc[4][4] = {};
    int kslot = tid & 7;
    int row   = tid >> 3;

    for (int k0 = 0; k0 < K; k0 += 32) {
        #pragma unroll
        for (int pass = 0; pass < 2; ++pass) {
            int r = row + pass * 32;
            int gr = m0 + r;
            float4 v = make_float4(0.f, 0.f, 0.f, 0.f);
            if (gr < G_N) v = *(const float4*)(h + (size_t)gr * K + k0 + kslot * 4);
            As[kslot*4+0][r] = v.x; As[kslot*4+1][r] = v.y;
            As[kslot*4+2][r] = v.z; As[kslot*4+3][r] = v.w;

            int j = r;
            float4 w4 = make_float4(0.f, 0.f, 0.f, 0.f);
            if (j < OUT_DIM) w4 = *(const float4*)(W + (size_t)j * K + k0 + kslot * 4);
            Bs[kslot*4+0][j] = w4.x; Bs[kslot*4+1][j] = w4.y;
            Bs[kslot*4+2][j] = w4.z; Bs[kslot*4+3][j] = w4.w;
        }
        __syncthreads();
        #pragma unroll 8
        for (int k = 0; k < 32; ++k) {
            float4 a4 = *(const float4*)&As[k][ty*4];
            float4 b4 = *(const float4*)&Bs[k][tx*4];
            float av[4] = {a4.x, a4.y, a4.z, a4.w};
            float bv[4] = {b4.x, b4.y, b4.z, b4.w};
            #pragma unroll
            for (int i = 0; i < 4; ++i)
                #pragma unroll
                for (int j = 0; j < 4; ++j)
                    acc[i][j] = fmaf(av[i], bv[j], acc[i][j]);
        }
        __syncthreads();
    }

    bool validc = (tx < 10);
    float bi[4];
    #pragma unroll
    for (int j = 0; j < 4; ++j) bi[j] = validc ? b[tx*4+j] : 0.0f;

    #pragma unroll
    for (int i = 0; i < 4; ++i) {
        int gr = m0 + ty*4 + i;
        float v[4];
        float mymax = -INFINITY;
        #pragma unroll
        for (int j = 0; j < 4; ++j) {
            v[j] = acc[i][j] + bi[j];
            if (validc) mymax = fmaxf(mymax, v[j]);
        }
        #pragma unroll
        for (int off = 1; off < 16; off <<= 1) mymax = fmaxf(mymax, __shfl_xor(mymax, off));
        float s = 0.0f;
        if (validc) {
            #pragma unroll
            for (int j = 0; j < 4; ++j) s += expf(v[j] - mymax);
        }
        #pragma unroll
        for (int off = 1; off < 16; off <<= 1) s += __shfl_xor(s, off);
        float lse = mymax + logf(s);
        if (gr < G_N && validc) {
            float4 o = make_float4(v[0]-lse, v[1]-lse, v[2]-lse, v[3]-lse);
            *(float4*)(out + (size_t)gr * OUT_DIM + tx*4) = o;
        }
    }
}

extern "C" void kernel_launch(void* const* d_in, const int* in_sizes, int n_in,
                              void* d_out, int out_size, void* d_ws, size_t ws_size,
                              hipStream_t stream) {
    const float* x      = (const float*)d_in[0];
    const int*   rows   = (const int*)d_in[1];
    const int*   cols   = (const int*)d_in[2];
    const float* vals   = (const float*)d_in[3];
    const float* lin1_w = (const float*)d_in[4];
    const float* lin1_b = (const float*)d_in[5];
    const float* left_w = (const float*)d_in[6];
    const float* right_w= (const float*)d_in[7];
    const float* eps    = (const float*)d_in[8];
    const float* lin2_w = (const float*)d_in[9];
    const float* lin2_b = (const float*)d_in[10];
    float* out = (float*)d_out;

    size_t bufElems = (size_t)NN * HC;                     // 9.6M
    float* h0 = (float*)d_ws;                              // 38.4 MB
    unsigned short* tb = (unsigned short*)(h0 + bufElems); // 19.2 MB
    int*   rp   = (int*)(tb + bufElems);                   // NN+1
    int*   wo   = rp + 150016;
    int*   bsum = wo + 150016;
    int*   gcur = bsum + 256;
    long long* pcv = (long long*)(gcur + 16);              // PCV_CAP * 8B = 33.6 MB

    // bucket buffers alias h0+tb region (used only before lin1)
    int*       rbuf  = (int*)d_ws;                         // 8*BCAP ints
    long long* cvbuf = (long long*)(rbuf + 8 * BCAP);      // 8*BCAP * 8B

    dim3 b256(256);
    const int NB_SCAN = (NN + 1023) / 1024;                // 147

    // --- CSR build (two-phase bucketed; reused by all 4 layers) ---
    hipMemsetAsync(wo, 0, (size_t)NN * sizeof(int), stream);
    hipMemsetAsync(pcv, 0, (size_t)PCV_CAP * sizeof(long long), stream);
    init_gcur_k<<<dim3(1), dim3(64), 0, stream>>>(gcur);
    bucket_part_k<<<dim3((NNZV + 2047) / 2048), b256, 0, stream>>>(
        rows, cols, vals, gcur, rbuf, cvbuf);
    hist_bucket_k<<<dim3(8 * 128), b256, 0, stream>>>(rbuf, gcur, wo);
    scan_block_k<<<dim3(NB_SCAN), b256, 0, stream>>>(wo, rp, bsum);
    scan_top_k<<<dim3(1), b256, 0, stream>>>(bsum, NB_SCAN);
    scan_add_k<<<dim3((NN + 256) / 256 + 1), b256, 0, stream>>>(rp, bsum);
    hipMemcpyAsync(wo, rp, (size_t)NN * sizeof(int), hipMemcpyDeviceToDevice, stream);
    scatter_bucket_k<<<dim3(8 * 128), b256, 0, stream>>>(rbuf, cvbuf, gcur, wo, pcv);

    // --- lin1 -> h0 (MFMA bf16) ---
    lin1_mfma<<<dim3((G_N + 63) / 64), b256, 0, stream>>>(x, lin1_w, lin1_b, h0);

    for (int l = 0; l < NL; ++l) {
        transform_mfma<<<dim3((NN + 63) / 64), b256, 0, stream>>>(
            h0, left_w + l * 9, right_w + l * HC * HC, tb);
        spmm_csr_fused<<<dim3((NN + 3) / 4), b256, 0, stream>>>(
            rp, pcv, tb, h0, eps, l);
    }

    lin2_ls_gemm<<<dim3((G_N + 63) / 64), b256, 0, stream>>>(h0, lin2_w, lin2_b, out);
}